// Round 3
// baseline (245.531 us; speedup 1.0000x reference)
//
#include <hip/hip_runtime.h>

#define IMG 512
#define OUTCH ((size_t)48 * 512 * 512)   // floats per output tensor
#define NTHREADS (48 * 64 * 64)          // one thread per 8x8 block: 196608

typedef float f32x4 __attribute__((ext_vector_type(4)));

// Orthonormal 8-point DCT-II matrix D[k][t]
__device__ constexpr float Dm[8][8] = {
  { 0.3535533905932738f, 0.3535533905932738f, 0.3535533905932738f, 0.3535533905932738f,
    0.3535533905932738f, 0.3535533905932738f, 0.3535533905932738f, 0.3535533905932738f},
  { 0.4903926402016152f, 0.4157348061512726f, 0.2777851165098011f, 0.0975451610080642f,
   -0.0975451610080642f,-0.2777851165098011f,-0.4157348061512726f,-0.4903926402016152f},
  { 0.4619397662556434f, 0.1913417161825449f,-0.1913417161825449f,-0.4619397662556434f,
   -0.4619397662556434f,-0.1913417161825449f, 0.1913417161825449f, 0.4619397662556434f},
  { 0.4157348061512726f,-0.0975451610080642f,-0.4903926402016152f,-0.2777851165098011f,
    0.2777851165098011f, 0.4903926402016152f, 0.0975451610080642f,-0.4157348061512726f},
  { 0.3535533905932738f,-0.3535533905932738f,-0.3535533905932738f, 0.3535533905932738f,
    0.3535533905932738f,-0.3535533905932738f,-0.3535533905932738f, 0.3535533905932738f},
  { 0.2777851165098011f,-0.4903926402016152f, 0.0975451610080642f, 0.4157348061512726f,
   -0.4157348061512726f,-0.0975451610080642f, 0.4903926402016152f,-0.2777851165098011f},
  { 0.1913417161825449f,-0.4619397662556434f, 0.4619397662556434f,-0.1913417161825449f,
   -0.1913417161825449f, 0.4619397662556434f,-0.4619397662556434f, 0.1913417161825449f},
  { 0.0975451610080642f,-0.2777851165098011f, 0.4157348061512726f,-0.4903926402016152f,
    0.4903926402016152f,-0.4157348061512726f, 0.2777851165098011f,-0.0975451610080642f},
};

// 8x8 zigzag order (validated by passing rounds 1-2)
__device__ constexpr int ZZ[8][8] = {
  {  0,  1,  5,  6, 14, 15, 27, 28},
  {  2,  4,  7, 13, 16, 26, 29, 42},
  {  3,  8, 12, 17, 25, 30, 41, 43},
  {  9, 11, 18, 24, 31, 40, 44, 53},
  { 10, 19, 23, 32, 39, 45, 52, 54},
  { 20, 22, 33, 38, 46, 51, 55, 60},
  { 21, 34, 37, 47, 50, 56, 59, 61},
  { 35, 36, 48, 49, 57, 58, 62, 63},
};

// Fused masked IDCT + store, one output row at a time (keeps live state at
// C[64] + 8 + 8 regs instead of materializing a second 64-float array).
// Mask (LO <= zz < HI) folds at compile time: zero-coeff FMAs are elided.
template <int LO, int HI>
__device__ __forceinline__ void idct_band_store(const float (&C)[8][8],
                                                float* __restrict__ dst,
                                                float scale) {
#pragma unroll
  for (int m = 0; m < 8; ++m) {
    // U[l] = sum_k Dm[k][m] * C_masked[k][l]   (21/21/22 FMAs per band)
    float U[8];
#pragma unroll
    for (int l = 0; l < 8; ++l) {
      float acc = 0.0f;
#pragma unroll
      for (int k = 0; k < 8; ++k)
        if (ZZ[k][l] >= LO && ZZ[k][l] < HI) acc += Dm[k][m] * C[k][l];
      U[l] = acc;
    }
    // sp[m][n] = sum_l U[l] * Dm[l][n]; scale; nontemporal store
    f32x4 v0, v1;
#pragma unroll
    for (int n = 0; n < 4; ++n) {
      float a0 = 0.0f, a1 = 0.0f;
#pragma unroll
      for (int l = 0; l < 8; ++l) {
        a0 += U[l] * Dm[l][n];
        a1 += U[l] * Dm[l][n + 4];
      }
      v0[n] = a0 * scale;
      v1[n] = a1 * scale;
    }
    __builtin_nontemporal_store(v0, (f32x4*)(dst + (size_t)m * IMG));
    __builtin_nontemporal_store(v1, (f32x4*)(dst + (size_t)m * IMG + 4));
  }
}

__global__ __launch_bounds__(256) void dct_decomp_kernel(
    const float* __restrict__ x, const float* __restrict__ band_scale,
    float* __restrict__ out) {
  int tid = blockIdx.x * 256 + threadIdx.x;

  // lane-adjacent threads take horizontally adjacent 8x8 blocks; a wave
  // covers one full 512-px block-row. No divergence, no cross-lane ops.
  int bw  = tid & 63;          // block col
  int bh  = (tid >> 6) & 63;   // block row
  int img = tid >> 12;         // b*3 + c, 0..47

  size_t base = ((size_t)img * IMG + (size_t)bh * 8) * IMG + (size_t)bw * 8;
  const float* src = x + base;

  // Load 8x8 block, all 16 loads issued up front (MLP), nontemporal.
  float X[8][8];
#pragma unroll
  for (int r = 0; r < 8; ++r) {
    f32x4 v0 = __builtin_nontemporal_load((const f32x4*)(src + (size_t)r * IMG));
    f32x4 v1 = __builtin_nontemporal_load((const f32x4*)(src + (size_t)r * IMG + 4));
    X[r][0] = v0[0]; X[r][1] = v0[1]; X[r][2] = v0[2]; X[r][3] = v0[3];
    X[r][4] = v1[0]; X[r][5] = v1[1]; X[r][6] = v1[2]; X[r][7] = v1[3];
  }

  // Forward DCT. Row pass in place: X[m][l] <- sum_n X[m][n]*Dm[l][n]
#pragma unroll
  for (int m = 0; m < 8; ++m) {
    float t[8];
#pragma unroll
    for (int l = 0; l < 8; ++l) {
      float acc = 0.0f;
#pragma unroll
      for (int n = 0; n < 8; ++n) acc += X[m][n] * Dm[l][n];
      t[l] = acc;
    }
#pragma unroll
    for (int l = 0; l < 8; ++l) X[m][l] = t[l];
  }
  // Column pass: C[k][l] = sum_m Dm[k][m]*X[m][l]
  float C[8][8];
#pragma unroll
  for (int l = 0; l < 8; ++l) {
#pragma unroll
    for (int k = 0; k < 8; ++k) {
      float acc = 0.0f;
#pragma unroll
      for (int m = 0; m < 8; ++m) acc += Dm[k][m] * X[m][l];
      C[k][l] = acc;
    }
  }

  float s0 = band_scale[0];
  float s1 = band_scale[1];
  float s2 = band_scale[2];

  // zigzag bands: low = [0,21), mid = [21,42), high = [42,64)
  idct_band_store< 0, 21>(C, out + base,             s0);
  idct_band_store<21, 42>(C, out + OUTCH + base,     s1);
  idct_band_store<42, 64>(C, out + 2 * OUTCH + base, s2);
}

extern "C" void kernel_launch(void* const* d_in, const int* in_sizes, int n_in,
                              void* d_out, int out_size, void* d_ws, size_t ws_size,
                              hipStream_t stream) {
  const float* x          = (const float*)d_in[0];
  const float* band_scale = (const float*)d_in[1];
  float* out              = (float*)d_out;

  dim3 grid(NTHREADS / 256);  // 768 workgroups
  dim3 block(256);
  dct_decomp_kernel<<<grid, block, 0, stream>>>(x, band_scale, out);
}